// Round 13
// baseline (311.662 us; speedup 1.0000x reference)
//
#include <hip/hip_runtime.h>

#define HW 3136
#define NB 32
#define NC 128

// Packed fp32 FMA helpers (VOP3P v_pk_fma_f32). op_sel/op_sel_hi broadcast
// the LO (b0) or HI (b1) word of src0 to both halves; pkn* fold negation.
static __device__ __forceinline__ float2 pka0(float2 c, float2 v, float2 a) {
  float2 d;
  asm("v_pk_fma_f32 %0, %1, %2, %3 op_sel:[0,0,0] op_sel_hi:[0,1,1]"
      : "=v"(d) : "v"(c), "v"(v), "v"(a));
  return d;
}
static __device__ __forceinline__ float2 pka1(float2 c, float2 v, float2 a) {
  float2 d;
  asm("v_pk_fma_f32 %0, %1, %2, %3 op_sel:[1,0,0] op_sel_hi:[1,1,1]"
      : "=v"(d) : "v"(c), "v"(v), "v"(a));
  return d;
}
static __device__ __forceinline__ float2 pkn0(float2 c, float2 v, float2 a) {
  float2 d;
  asm("v_pk_fma_f32 %0, %1, %2, %3 op_sel:[0,0,0] op_sel_hi:[0,1,1] neg_lo:[1,0,0] neg_hi:[1,0,0]"
      : "=v"(d) : "v"(c), "v"(v), "v"(a));
  return d;
}
static __device__ __forceinline__ float2 pkn1(float2 c, float2 v, float2 a) {
  float2 d;
  asm("v_pk_fma_f32 %0, %1, %2, %3 op_sel:[1,0,0] op_sel_hi:[1,1,1] neg_lo:[1,0,0] neg_hi:[1,0,0]"
      : "=v"(d) : "v"(c), "v"(v), "v"(a));
  return d;
}

// 512 threads: thread owns 8 rows x 4 cols (rm = t>>5, cm = t&31).
// Rank-2 sweep steps (pivots k,k+1), 64 barriers. LDS: Hb/Gb UNION Xs
// (Xs dead after covariance) -> ~17KB total -> 4 blocks/CU co-resident
// (wave-slot limited), vs ~2.4 before. __launch_bounds__(512,8) caps
// VGPR at 64 (R10 measured 40 -> fits, no spill).
__global__ __launch_bounds__(512, 8)
void mvg_kernel(const float* __restrict__ emb, float* __restrict__ out) {
  // XCD-bijective swizzle (3136 = 8*392): contiguous pos chunk per XCD.
  const int bid = blockIdx.x;
  const int pos = (bid & 7) * 392 + (bid >> 3);
  const int t = threadIdx.x;
  const int rm = t >> 5;
  const int cm = t & 31;
  const int i0 = rm << 3;
  const int c0 = cm << 2;

  // arena[0..4095] = Xs (dense 32x128), later overlaid by Hb (528 floats)
  // and Gb (528 floats). ms lives beyond Xs (arena[4096..4223]).
  __shared__ __align__(16) float arena[4224];
  float* Xs = arena;
  float (*Hb)[2][132] = (float (*)[2][132])(arena);        // [parity][j][132]
  float (*Gb)[2][132] = (float (*)[2][132])(arena + 528);
  float* ms = arena + 4096;

  // ---- gather the (B, C) slice ----
  #pragma unroll
  for (int m = 0; m < 8; ++m) {
    const int idx = t + 512 * m;
    const int b = idx >> 7;
    const int c = idx & (NC - 1);
    Xs[idx] = emb[(size_t)b * (size_t)(NC * HW) + (size_t)c * HW + pos];
  }
  __syncthreads();

  // ---- mean over batch, write mean output ----
  if (t < NC) {
    float s = 0.f;
    #pragma unroll
    for (int b = 0; b < NB; ++b) s += Xs[b * NC + t];
    const float m = s * (1.0f / NB);
    ms[t] = m;
    out[(size_t)t * HW + pos] = m;
  }
  __syncthreads();

  // ---- center ----
  #pragma unroll
  for (int m = 0; m < 8; ++m) {
    const int idx = t + 512 * m;
    Xs[idx] -= ms[idx & (NC - 1)];
  }
  __syncthreads();

  float2 aP[8][2];
  #pragma unroll
  for (int r = 0; r < 8; ++r) {
    aP[r][0] = make_float2(0.f, 0.f);
    aP[r][1] = make_float2(0.f, 0.f);
  }

  // ---- covariance accumulate (packed) ----
  for (int b = 0; b < NB; ++b) {
    const float* xr = &Xs[b * NC];
    const float4 rv  = *(const float4*)&xr[c0];
    const float4 cv0 = *(const float4*)&xr[i0];
    const float4 cv1 = *(const float4*)&xr[i0 + 4];
    const float2 rL = make_float2(rv.x, rv.y), rH = make_float2(rv.z, rv.w);
    const float2 c01 = make_float2(cv0.x, cv0.y), c23 = make_float2(cv0.z, cv0.w);
    const float2 c45 = make_float2(cv1.x, cv1.y), c67 = make_float2(cv1.z, cv1.w);
    aP[0][0] = pka0(c01, rL, aP[0][0]); aP[0][1] = pka0(c01, rH, aP[0][1]);
    aP[1][0] = pka1(c01, rL, aP[1][0]); aP[1][1] = pka1(c01, rH, aP[1][1]);
    aP[2][0] = pka0(c23, rL, aP[2][0]); aP[2][1] = pka0(c23, rH, aP[2][1]);
    aP[3][0] = pka1(c23, rL, aP[3][0]); aP[3][1] = pka1(c23, rH, aP[3][1]);
    aP[4][0] = pka0(c45, rL, aP[4][0]); aP[4][1] = pka0(c45, rH, aP[4][1]);
    aP[5][0] = pka1(c45, rL, aP[5][0]); aP[5][1] = pka1(c45, rH, aP[5][1]);
    aP[6][0] = pka0(c67, rL, aP[6][0]); aP[6][1] = pka0(c67, rH, aP[6][1]);
    aP[7][0] = pka1(c67, rL, aP[7][0]); aP[7][1] = pka1(c67, rH, aP[7][1]);
  }

  // ---- scale 1/(B-1), + (REG_DIAG+REG_EPS) I ----
  {
    const float s31 = 1.0f / (float)(NB - 1);
    const float RD = 0.01f + 1e-5f;
    #pragma unroll
    for (int r = 0; r < 8; ++r) {
      const int gr = i0 + r;
      aP[r][0].x = aP[r][0].x * s31 + ((gr == c0 + 0) ? RD : 0.f);
      aP[r][0].y = aP[r][0].y * s31 + ((gr == c0 + 1) ? RD : 0.f);
      aP[r][1].x = aP[r][1].x * s31 + ((gr == c0 + 2) ? RD : 0.f);
      aP[r][1].y = aP[r][1].y * s31 + ((gr == c0 + 3) ? RD : 0.f);
    }
  }
  __syncthreads();   // arena reuse: all Xs reads done before H/G writes

  // PAIR: rank-2 sweep step (pivots k=8Q+2J, k+1), h-encoded; identical math
  // to R9/R10 (passed, absmax 0.5). Owner = the half-wave rm==Q.
  #define PAIR(Q, J, PB, CK, CK1, JH) {                                     \
    if (rm == (Q)) {                                                        \
      const int cmd = 2 * (Q) + (JH);                                       \
      float4 hk = make_float4(aP[2*(J)][0].x, aP[2*(J)][0].y,               \
                              aP[2*(J)][1].x, aP[2*(J)][1].y);              \
      if (cm == cmd) hk.CK -= 1.0f;                                         \
      const float d0 = __shfl(hk.CK, cmd, 32) + 1.0f;                       \
      const float rd0 = __builtin_amdgcn_rcpf(d0);                          \
      float4 gk;                                                            \
      gk.x = hk.x * rd0; gk.y = hk.y * rd0;                                 \
      gk.z = hk.z * rd0; gk.w = hk.w * rd0;                                 \
      const float ck1 = __shfl(gk.CK1, cmd, 32);                            \
      float4 hs;                                                            \
      hs.x = fmaf(-ck1, hk.x, aP[2*(J)+1][0].x);                            \
      hs.y = fmaf(-ck1, hk.y, aP[2*(J)+1][0].y);                            \
      hs.z = fmaf(-ck1, hk.z, aP[2*(J)+1][1].x);                            \
      hs.w = fmaf(-ck1, hk.w, aP[2*(J)+1][1].y);                            \
      if (cm == cmd) hs.CK1 -= 1.0f;                                        \
      const float d1 = __shfl(hs.CK1, cmd, 32) + 1.0f;                      \
      const float rd1 = __builtin_amdgcn_rcpf(d1);                          \
      float4 gs;                                                            \
      gs.x = hs.x * rd1; gs.y = hs.y * rd1;                                 \
      gs.z = hs.z * rd1; gs.w = hs.w * rd1;                                 \
      *(float4*)&Hb[PB][0][c0] = hk;                                        \
      *(float4*)&Hb[PB][1][c0] = hs;                                        \
      *(float4*)&Gb[PB][0][c0] = gk;                                        \
      *(float4*)&Gb[PB][1][c0] = gs;                                        \
    }                                                                       \
    __syncthreads();                                                        \
    {                                                                       \
      const float4 hr4 = *(const float4*)&Hb[PB][0][c0];                    \
      const float4 hs4 = *(const float4*)&Hb[PB][1][c0];                    \
      const float4 ga0 = *(const float4*)&Gb[PB][0][i0];                    \
      const float4 ga1 = *(const float4*)&Gb[PB][0][i0 + 4];                \
      const float4 gb0 = *(const float4*)&Gb[PB][1][i0];                    \
      const float4 gb1 = *(const float4*)&Gb[PB][1][i0 + 4];                \
      const float2 hrL = make_float2(hr4.x, hr4.y);                         \
      const float2 hrH = make_float2(hr4.z, hr4.w);                         \
      const float2 hsL = make_float2(hs4.x, hs4.y);                         \
      const float2 hsH = make_float2(hs4.z, hs4.w);                         \
      const float2 A01 = make_float2(ga0.x, ga0.y);                         \
      const float2 A23 = make_float2(ga0.z, ga0.w);                         \
      const float2 A45 = make_float2(ga1.x, ga1.y);                         \
      const float2 A67 = make_float2(ga1.z, ga1.w);                         \
      const float2 B01 = make_float2(gb0.x, gb0.y);                         \
      const float2 B23 = make_float2(gb0.z, gb0.w);                         \
      const float2 B45 = make_float2(gb1.x, gb1.y);                         \
      const float2 B67 = make_float2(gb1.z, gb1.w);                         \
      aP[0][0] = pkn0(A01, hrL, pkn0(B01, hsL, aP[0][0]));                  \
      aP[0][1] = pkn0(A01, hrH, pkn0(B01, hsH, aP[0][1]));                  \
      aP[1][0] = pkn1(A01, hrL, pkn1(B01, hsL, aP[1][0]));                  \
      aP[1][1] = pkn1(A01, hrH, pkn1(B01, hsH, aP[1][1]));                  \
      aP[2][0] = pkn0(A23, hrL, pkn0(B23, hsL, aP[2][0]));                  \
      aP[2][1] = pkn0(A23, hrH, pkn0(B23, hsH, aP[2][1]));                  \
      aP[3][0] = pkn1(A23, hrL, pkn1(B23, hsL, aP[3][0]));                  \
      aP[3][1] = pkn1(A23, hrH, pkn1(B23, hsH, aP[3][1]));                  \
      aP[4][0] = pkn0(A45, hrL, pkn0(B45, hsL, aP[4][0]));                  \
      aP[4][1] = pkn0(A45, hrH, pkn0(B45, hsH, aP[4][1]));                  \
      aP[5][0] = pkn1(A45, hrL, pkn1(B45, hsL, aP[5][0]));                  \
      aP[5][1] = pkn1(A45, hrH, pkn1(B45, hsH, aP[5][1]));                  \
      aP[6][0] = pkn0(A67, hrL, pkn0(B67, hsL, aP[6][0]));                  \
      aP[6][1] = pkn0(A67, hrH, pkn0(B67, hsH, aP[6][1]));                  \
      aP[7][0] = pkn1(A67, hrL, pkn1(B67, hsL, aP[7][0]));                  \
      aP[7][1] = pkn1(A67, hrH, pkn1(B67, hsH, aP[7][1]));                  \
    }                                                                       \
  }

  // ---- 64 rank-2 steps: 16 iterations x 4 static pairs ----
  #pragma unroll 1
  for (int q = 0; q < 16; ++q) {
    PAIR(q, 0, 0, x, y, 0)    // k = 8q+0
    PAIR(q, 1, 1, z, w, 0)    // k = 8q+2
    PAIR(q, 2, 0, x, y, 1)    // k = 8q+4
    PAIR(q, 3, 1, z, w, 1)    // k = 8q+6
  }

  // ---- store: inv = -a, diag = 2 - a (undo the +2 encoding artifact) ----
  float* o = out + (size_t)NC * HW + (size_t)pos * (NC * NC);
  #pragma unroll
  for (int r = 0; r < 8; ++r) {
    const int gr = i0 + r;
    float4 w;
    w.x = (gr == c0 + 0) ? (2.0f - aP[r][0].x) : (-aP[r][0].x);
    w.y = (gr == c0 + 1) ? (2.0f - aP[r][0].y) : (-aP[r][0].y);
    w.z = (gr == c0 + 2) ? (2.0f - aP[r][1].x) : (-aP[r][1].x);
    w.w = (gr == c0 + 3) ? (2.0f - aP[r][1].y) : (-aP[r][1].y);
    *(float4*)&o[(size_t)gr * NC + c0] = w;
  }
}

extern "C" void kernel_launch(void* const* d_in, const int* in_sizes, int n_in,
                              void* d_out, int out_size, void* d_ws, size_t ws_size,
                              hipStream_t stream) {
  const float* emb = (const float*)d_in[0];
  float* out = (float*)d_out;
  mvg_kernel<<<HW, 512, 0, stream>>>(emb, out);
}

// Round 15
// 155.537 us; speedup vs baseline: 2.0038x; 2.0038x over previous
//
#include <hip/hip_runtime.h>

#define HW 3136
#define NB 32
#define NC 128
#define XST 132          // Xc/W row stride (floats), 16B-aligned rows
#define SST 36           // S/Sinv row stride
#define LAMV 0.01001f    // REG_DIAG + REG_EPS

// VOP3P v_pk_fma_f32 helpers (proven R10-R13). pka0/pka1 broadcast LO/HI
// word of src0 to both halves; pke is plain elementwise.
static __device__ __forceinline__ float2 pka0(float2 c, float2 v, float2 a) {
  float2 d;
  asm("v_pk_fma_f32 %0, %1, %2, %3 op_sel:[0,0,0] op_sel_hi:[0,1,1]"
      : "=v"(d) : "v"(c), "v"(v), "v"(a));
  return d;
}
static __device__ __forceinline__ float2 pka1(float2 c, float2 v, float2 a) {
  float2 d;
  asm("v_pk_fma_f32 %0, %1, %2, %3 op_sel:[1,0,0] op_sel_hi:[1,1,1]"
      : "=v"(d) : "v"(c), "v"(v), "v"(a));
  return d;
}
static __device__ __forceinline__ float2 pke(float2 a, float2 b, float2 c) {
  float2 d;
  asm("v_pk_fma_f32 %0, %1, %2, %3"
      : "=v"(d) : "v"(a), "v"(b), "v"(c));
  return d;
}

// Woodbury: Ainv = (1/lam)[I - Xc^T Sinv Xc / 31], S = lam I + Xc Xc^T / 31.
// P2 (32x32 sweep) runs on wave 0 with SHUFFLE-ONLY broadcasts (no LDS in
// the pivot loop; register dataflow the compiler must order correctly).
__global__ __launch_bounds__(512, 8)
void mvg_kernel(const float* __restrict__ emb, float* __restrict__ out) {
  // XCD-bijective swizzle (3136 = 8*392): contiguous pos chunk per XCD.
  const int bid = blockIdx.x;
  const int pos = (bid & 7) * 392 + (bid >> 3);
  const int t = threadIdx.x;

  __shared__ __align__(16) float XcB[NB * XST];   // 16.9 KB, live all phases
  __shared__ __align__(16) float WB[NB * XST];    // 16.9 KB, P3/P4
  __shared__ __align__(16) float SB[32 * SST];    // 4.6 KB: S then Sinv
  __shared__ float ms[NC];

  // ---- gather (B, C) slice ----
  #pragma unroll
  for (int m = 0; m < 8; ++m) {
    const int idx = t + 512 * m;
    const int b = idx >> 7;
    const int c = idx & (NC - 1);
    XcB[b * XST + c] = emb[(size_t)b * (size_t)(NC * HW) + (size_t)c * HW + pos];
  }
  __syncthreads();

  // ---- mean, write mean output ----
  if (t < NC) {
    float s = 0.f;
    #pragma unroll
    for (int b = 0; b < NB; ++b) s += XcB[b * XST + t];
    const float m = s * (1.0f / NB);
    ms[t] = m;
    out[(size_t)t * HW + pos] = m;
  }
  __syncthreads();

  // ---- center ----
  #pragma unroll
  for (int m = 0; m < 8; ++m) {
    const int idx = t + 512 * m;
    const int b = idx >> 7;
    const int c = idx & (NC - 1);
    XcB[b * XST + c] -= ms[c];
  }
  __syncthreads();

  // ---- P1: S = lam*I + Xc Xc^T / 31 ----
  {
    const int i = t >> 4;
    const int j2 = t & 15;
    const float* xi = &XcB[i * XST];
    const float* xa = &XcB[(2 * j2) * XST];
    const float* xb = &XcB[(2 * j2 + 1) * XST];
    float2 accA = make_float2(0.f, 0.f), accB = make_float2(0.f, 0.f);
    #pragma unroll 8
    for (int c = 0; c < NC; c += 4) {
      const float4 vi = *(const float4*)&xi[c];
      const float4 va = *(const float4*)&xa[c];
      const float4 vb = *(const float4*)&xb[c];
      const float2 viL = make_float2(vi.x, vi.y), viH = make_float2(vi.z, vi.w);
      accA = pke(viL, make_float2(va.x, va.y), accA);
      accA = pke(viH, make_float2(va.z, va.w), accA);
      accB = pke(viL, make_float2(vb.x, vb.y), accB);
      accB = pke(viH, make_float2(vb.z, vb.w), accB);
    }
    const float s31 = 1.0f / 31.0f;
    SB[i * SST + 2 * j2]     = (accA.x + accA.y) * s31 + ((i == 2 * j2)     ? LAMV : 0.f);
    SB[i * SST + 2 * j2 + 1] = (accB.x + accB.y) * s31 + ((i == 2 * j2 + 1) ? LAMV : 0.f);
  }
  __syncthreads();

  // ---- P2: wave 0 sweeps S (32 pivots) with shuffle broadcasts only.
  //      Lane (r = t&31, h = t>>5) owns S row r, cols [16h, 16h+16).
  //      Per pivot K: pc = my column-K entry (h-encoded -1 at r==K), valid in
  //      the half h==K>>4; all broadcasts source lanes 32*(K>>4)+row.
  //      By symmetry pivot row == pivot column. Exact (verified 2x2).
  if (t < 64) {
    const int r = t & 31;
    const int hb = (t >> 5) << 4;     // 16*h, my column base
    float m[16];
    #pragma unroll
    for (int j = 0; j < 4; ++j) {
      const float4 v = *(const float4*)&SB[r * SST + hb + 4 * j];
      m[4 * j] = v.x; m[4 * j + 1] = v.y; m[4 * j + 2] = v.z; m[4 * j + 3] = v.w;
    }

    #define SWEEP_K(K) {                                                    \
      float pc = m[(K) & 15] - ((r == (K)) ? 1.0f : 0.0f);                  \
      const float dm1 = __shfl(pc, (((K) >> 4) << 5) + (K), 64);            \
      const float cr  = __shfl(pc, (((K) >> 4) << 5) + r, 64);              \
      const float g = cr * __builtin_amdgcn_rcpf(dm1 + 1.0f);               \
      float hj[16];                                                         \
      _Pragma("unroll")                                                     \
      for (int j = 0; j < 16; ++j)                                          \
        hj[j] = __shfl(pc, (((K) >> 4) << 5) + hb + j, 64);                 \
      _Pragma("unroll")                                                     \
      for (int j = 0; j < 16; ++j) m[j] = fmaf(-g, hj[j], m[j]);            \
    }

    SWEEP_K(0)  SWEEP_K(1)  SWEEP_K(2)  SWEEP_K(3)
    SWEEP_K(4)  SWEEP_K(5)  SWEEP_K(6)  SWEEP_K(7)
    SWEEP_K(8)  SWEEP_K(9)  SWEEP_K(10) SWEEP_K(11)
    SWEEP_K(12) SWEEP_K(13) SWEEP_K(14) SWEEP_K(15)
    SWEEP_K(16) SWEEP_K(17) SWEEP_K(18) SWEEP_K(19)
    SWEEP_K(20) SWEEP_K(21) SWEEP_K(22) SWEEP_K(23)
    SWEEP_K(24) SWEEP_K(25) SWEEP_K(26) SWEEP_K(27)
    SWEEP_K(28) SWEEP_K(29) SWEEP_K(30) SWEEP_K(31)

    // Sinv = -(swept), diag = 2 - (swept)
    #pragma unroll
    for (int j = 0; j < 16; ++j) {
      const int col = hb + j;
      SB[r * SST + col] = (col == r) ? (2.0f - m[j]) : (-m[j]);
    }
  }
  __syncthreads();

  // ---- P3: W = Sinv * Xc (32x128) ----
  {
    const int s = t >> 4;
    const int C0 = (t & 15) << 3;
    float2 w01 = make_float2(0.f, 0.f), w23 = make_float2(0.f, 0.f);
    float2 w45 = make_float2(0.f, 0.f), w67 = make_float2(0.f, 0.f);
    #pragma unroll 2
    for (int j = 0; j < 32; j += 4) {
      const float4 sv = *(const float4*)&SB[s * SST + j];
      const float2 svL = make_float2(sv.x, sv.y);
      const float2 svH = make_float2(sv.z, sv.w);
      {
        const float* xr = &XcB[(j + 0) * XST + C0];
        const float4 a = *(const float4*)xr;
        const float4 b = *(const float4*)(xr + 4);
        w01 = pka0(svL, make_float2(a.x, a.y), w01);
        w23 = pka0(svL, make_float2(a.z, a.w), w23);
        w45 = pka0(svL, make_float2(b.x, b.y), w45);
        w67 = pka0(svL, make_float2(b.z, b.w), w67);
      }
      {
        const float* xr = &XcB[(j + 1) * XST + C0];
        const float4 a = *(const float4*)xr;
        const float4 b = *(const float4*)(xr + 4);
        w01 = pka1(svL, make_float2(a.x, a.y), w01);
        w23 = pka1(svL, make_float2(a.z, a.w), w23);
        w45 = pka1(svL, make_float2(b.x, b.y), w45);
        w67 = pka1(svL, make_float2(b.z, b.w), w67);
      }
      {
        const float* xr = &XcB[(j + 2) * XST + C0];
        const float4 a = *(const float4*)xr;
        const float4 b = *(const float4*)(xr + 4);
        w01 = pka0(svH, make_float2(a.x, a.y), w01);
        w23 = pka0(svH, make_float2(a.z, a.w), w23);
        w45 = pka0(svH, make_float2(b.x, b.y), w45);
        w67 = pka0(svH, make_float2(b.z, b.w), w67);
      }
      {
        const float* xr = &XcB[(j + 3) * XST + C0];
        const float4 a = *(const float4*)xr;
        const float4 b = *(const float4*)(xr + 4);
        w01 = pka1(svH, make_float2(a.x, a.y), w01);
        w23 = pka1(svH, make_float2(a.z, a.w), w23);
        w45 = pka1(svH, make_float2(b.x, b.y), w45);
        w67 = pka1(svH, make_float2(b.z, b.w), w67);
      }
    }
    *(float4*)&WB[s * XST + C0]     = make_float4(w01.x, w01.y, w23.x, w23.y);
    *(float4*)&WB[s * XST + C0 + 4] = make_float4(w45.x, w45.y, w67.x, w67.y);
  }
  __syncthreads();

  // ---- P4: P = Xc^T W (128x128) + epilogue ----
  {
    const int rm = t >> 5;
    const int cm = t & 31;
    const int i0 = rm << 3;
    const int c0 = cm << 2;
    float2 aP[8][2];
    #pragma unroll
    for (int r = 0; r < 8; ++r) {
      aP[r][0] = make_float2(0.f, 0.f);
      aP[r][1] = make_float2(0.f, 0.f);
    }
    #pragma unroll 4
    for (int s = 0; s < 32; ++s) {
      const float4 cv0 = *(const float4*)&XcB[s * XST + i0];
      const float4 cv1 = *(const float4*)&XcB[s * XST + i0 + 4];
      const float4 rv  = *(const float4*)&WB[s * XST + c0];
      const float2 rL = make_float2(rv.x, rv.y), rH = make_float2(rv.z, rv.w);
      const float2 c01 = make_float2(cv0.x, cv0.y), c23 = make_float2(cv0.z, cv0.w);
      const float2 c45 = make_float2(cv1.x, cv1.y), c67 = make_float2(cv1.z, cv1.w);
      aP[0][0] = pka0(c01, rL, aP[0][0]); aP[0][1] = pka0(c01, rH, aP[0][1]);
      aP[1][0] = pka1(c01, rL, aP[1][0]); aP[1][1] = pka1(c01, rH, aP[1][1]);
      aP[2][0] = pka0(c23, rL, aP[2][0]); aP[2][1] = pka0(c23, rH, aP[2][1]);
      aP[3][0] = pka1(c23, rL, aP[3][0]); aP[3][1] = pka1(c23, rH, aP[3][1]);
      aP[4][0] = pka0(c45, rL, aP[4][0]); aP[4][1] = pka0(c45, rH, aP[4][1]);
      aP[5][0] = pka1(c45, rL, aP[5][0]); aP[5][1] = pka1(c45, rH, aP[5][1]);
      aP[6][0] = pka0(c67, rL, aP[6][0]); aP[6][1] = pka0(c67, rH, aP[6][1]);
      aP[7][0] = pka1(c67, rL, aP[7][0]); aP[7][1] = pka1(c67, rH, aP[7][1]);
    }
    // Ainv = ILAM*I - (ILAM/31) * P
    const float ILAM = 1.0f / LAMV;
    const float IL31 = ILAM / 31.0f;
    float* o = out + (size_t)NC * HW + (size_t)pos * (NC * NC);
    #pragma unroll
    for (int r = 0; r < 8; ++r) {
      const int gr = i0 + r;
      float4 w;
      w.x = fmaf(-IL31, aP[r][0].x, (gr == c0 + 0) ? ILAM : 0.f);
      w.y = fmaf(-IL31, aP[r][0].y, (gr == c0 + 1) ? ILAM : 0.f);
      w.z = fmaf(-IL31, aP[r][1].x, (gr == c0 + 2) ? ILAM : 0.f);
      w.w = fmaf(-IL31, aP[r][1].y, (gr == c0 + 3) ? ILAM : 0.f);
      *(float4*)&o[(size_t)gr * NC + c0] = w;
    }
  }
}

extern "C" void kernel_launch(void* const* d_in, const int* in_sizes, int n_in,
                              void* d_out, int out_size, void* d_ws, size_t ws_size,
                              hipStream_t stream) {
  const float* emb = (const float*)d_in[0];
  float* out = (float*)d_out;
  mvg_kernel<<<HW, 512, 0, stream>>>(emb, out);
}

// Round 16
// 145.811 us; speedup vs baseline: 2.1374x; 1.0667x over previous
//
#include <hip/hip_runtime.h>

#define HW 3136
#define NB 32
#define NC 128
#define XST 132          // Xc/W row stride (floats), 16B-aligned rows
#define SST 36           // S/Sinv row stride
#define LAMV 0.01001f    // REG_DIAG + REG_EPS
// Row permutation: even rows -> slots 0..15, odd rows -> slots 16..31.
// Makes every strided row-read 2-way bank aliased (free) instead of 4-way.
#define SIG(r) (((((r) & 1)) << 4) | ((r) >> 1))

// VOP3P v_pk_fma_f32 helpers (proven R10-R15). pka0/pka1 broadcast LO/HI
// word of src0 to both halves; pke is plain elementwise.
static __device__ __forceinline__ float2 pka0(float2 c, float2 v, float2 a) {
  float2 d;
  asm("v_pk_fma_f32 %0, %1, %2, %3 op_sel:[0,0,0] op_sel_hi:[0,1,1]"
      : "=v"(d) : "v"(c), "v"(v), "v"(a));
  return d;
}
static __device__ __forceinline__ float2 pka1(float2 c, float2 v, float2 a) {
  float2 d;
  asm("v_pk_fma_f32 %0, %1, %2, %3 op_sel:[1,0,0] op_sel_hi:[1,1,1]"
      : "=v"(d) : "v"(c), "v"(v), "v"(a));
  return d;
}
static __device__ __forceinline__ float2 pke(float2 a, float2 b, float2 c) {
  float2 d;
  asm("v_pk_fma_f32 %0, %1, %2, %3"
      : "=v"(d) : "v"(a), "v"(b), "v"(c));
  return d;
}

__global__ __launch_bounds__(512, 8)
void mvg_kernel(const float* __restrict__ emb, float* __restrict__ out) {
  // XCD-bijective swizzle (3136 = 8*392): contiguous pos chunk per XCD.
  const int bid = blockIdx.x;
  const int pos = (bid & 7) * 392 + (bid >> 3);
  const int t = threadIdx.x;

  __shared__ __align__(16) float XcB[NB * XST];   // sigma-permuted rows
  __shared__ __align__(16) float WB[NB * XST];    // sigma-permuted rows
  __shared__ __align__(16) float SB[32 * SST];    // sigma-permuted rows
  __shared__ float ms[NC];

  // ---- gather (B, C) slice into permuted slots ----
  #pragma unroll
  for (int m = 0; m < 8; ++m) {
    const int idx = t + 512 * m;
    const int b = idx >> 7;
    const int c = idx & (NC - 1);
    XcB[SIG(b) * XST + c] = emb[(size_t)b * (size_t)(NC * HW) + (size_t)c * HW + pos];
  }
  __syncthreads();

  // ---- mean (sum over all slots == sum over rows), write mean output ----
  if (t < NC) {
    float s = 0.f;
    #pragma unroll
    for (int b = 0; b < NB; ++b) s += XcB[b * XST + t];
    const float m = s * (1.0f / NB);
    ms[t] = m;
    out[(size_t)t * HW + pos] = m;
  }
  __syncthreads();

  // ---- center (uniform over slots) ----
  #pragma unroll
  for (int m = 0; m < 8; ++m) {
    const int idx = t + 512 * m;
    const int b = idx >> 7;
    const int c = idx & (NC - 1);
    XcB[b * XST + c] -= ms[c];
  }
  __syncthreads();

  // ---- P1: S = lam*I + Xc Xc^T / 31, 2x2 tiles on 256 threads ----
  if (t < 256) {
    const int I = t >> 4;
    const int J = t & 15;
    const float* xi0 = &XcB[I * XST];           // row 2I
    const float* xi1 = &XcB[(16 + I) * XST];    // row 2I+1
    const float* xj0 = &XcB[J * XST];           // row 2J
    const float* xj1 = &XcB[(16 + J) * XST];    // row 2J+1
    float2 d00 = make_float2(0.f, 0.f), d01 = make_float2(0.f, 0.f);
    float2 d10 = make_float2(0.f, 0.f), d11 = make_float2(0.f, 0.f);
    #pragma unroll 8
    for (int c = 0; c < NC; c += 4) {
      const float4 a0 = *(const float4*)&xi0[c];
      const float4 a1 = *(const float4*)&xi1[c];
      const float4 b0 = *(const float4*)&xj0[c];
      const float4 b1 = *(const float4*)&xj1[c];
      const float2 a0L = make_float2(a0.x, a0.y), a0H = make_float2(a0.z, a0.w);
      const float2 a1L = make_float2(a1.x, a1.y), a1H = make_float2(a1.z, a1.w);
      const float2 b0L = make_float2(b0.x, b0.y), b0H = make_float2(b0.z, b0.w);
      const float2 b1L = make_float2(b1.x, b1.y), b1H = make_float2(b1.z, b1.w);
      d00 = pke(a0L, b0L, d00); d00 = pke(a0H, b0H, d00);
      d01 = pke(a0L, b1L, d01); d01 = pke(a0H, b1H, d01);
      d10 = pke(a1L, b0L, d10); d10 = pke(a1H, b0H, d10);
      d11 = pke(a1L, b1L, d11); d11 = pke(a1H, b1H, d11);
    }
    const float s31 = 1.0f / 31.0f;
    const float dg = (I == J) ? LAMV : 0.f;
    float2 e0, e1;
    e0.x = (d00.x + d00.y) * s31 + dg;          // (2I,   2J)
    e0.y = (d01.x + d01.y) * s31;               // (2I,   2J+1)
    e1.x = (d10.x + d10.y) * s31;               // (2I+1, 2J)
    e1.y = (d11.x + d11.y) * s31 + dg;          // (2I+1, 2J+1)
    *(float2*)&SB[I * SST + 2 * J] = e0;        // row 2I   -> slot I
    *(float2*)&SB[(16 + I) * SST + 2 * J] = e1; // row 2I+1 -> slot 16+I
  }
  __syncthreads();

  // ---- P2: wave 0 sweeps S (32 pivots) with shuffle-only broadcasts ----
  if (t < 64) {
    const int r = t & 31;
    const int hb = (t >> 5) << 4;
    const int rs = SIG(r);                      // storage slot of row r
    float m[16];
    #pragma unroll
    for (int j = 0; j < 4; ++j) {
      const float4 v = *(const float4*)&SB[rs * SST + hb + 4 * j];
      m[4 * j] = v.x; m[4 * j + 1] = v.y; m[4 * j + 2] = v.z; m[4 * j + 3] = v.w;
    }

    #define SWEEP_K(K) {                                                    \
      float pc = m[(K) & 15] - ((r == (K)) ? 1.0f : 0.0f);                  \
      const float dm1 = __shfl(pc, (((K) >> 4) << 5) + (K), 64);            \
      const float cr  = __shfl(pc, (((K) >> 4) << 5) + r, 64);              \
      const float g = cr * __builtin_amdgcn_rcpf(dm1 + 1.0f);               \
      float hj[16];                                                         \
      _Pragma("unroll")                                                     \
      for (int j = 0; j < 16; ++j)                                          \
        hj[j] = __shfl(pc, (((K) >> 4) << 5) + hb + j, 64);                 \
      _Pragma("unroll")                                                     \
      for (int j = 0; j < 16; ++j) m[j] = fmaf(-g, hj[j], m[j]);            \
    }

    SWEEP_K(0)  SWEEP_K(1)  SWEEP_K(2)  SWEEP_K(3)
    SWEEP_K(4)  SWEEP_K(5)  SWEEP_K(6)  SWEEP_K(7)
    SWEEP_K(8)  SWEEP_K(9)  SWEEP_K(10) SWEEP_K(11)
    SWEEP_K(12) SWEEP_K(13) SWEEP_K(14) SWEEP_K(15)
    SWEEP_K(16) SWEEP_K(17) SWEEP_K(18) SWEEP_K(19)
    SWEEP_K(20) SWEEP_K(21) SWEEP_K(22) SWEEP_K(23)
    SWEEP_K(24) SWEEP_K(25) SWEEP_K(26) SWEEP_K(27)
    SWEEP_K(28) SWEEP_K(29) SWEEP_K(30) SWEEP_K(31)

    #pragma unroll
    for (int j = 0; j < 16; ++j) {
      const int col = hb + j;
      SB[rs * SST + col] = (col == r) ? (2.0f - m[j]) : (-m[j]);
    }
  }
  __syncthreads();

  // ---- P3: W = Sinv * Xc; thread owns rows (2s2, 2s2+1) x 8 cols ----
  if (t < 256) {
    const int s2 = t >> 4;
    const int C0 = (t & 15) << 3;
    float2 w0[4], w1[4];
    #pragma unroll
    for (int q = 0; q < 4; ++q) {
      w0[q] = make_float2(0.f, 0.f);
      w1[q] = make_float2(0.f, 0.f);
    }
    #pragma unroll 2
    for (int j = 0; j < 32; j += 4) {
      const float4 sv0 = *(const float4*)&SB[s2 * SST + j];         // row 2s2
      const float4 sv1 = *(const float4*)&SB[(16 + s2) * SST + j];  // row 2s2+1
      const float2 s0L = make_float2(sv0.x, sv0.y), s0H = make_float2(sv0.z, sv0.w);
      const float2 s1L = make_float2(sv1.x, sv1.y), s1H = make_float2(sv1.z, sv1.w);
      const int jh = j >> 1;
      const float* xr0 = &XcB[jh * XST + C0];          // row j   (slot j/2)
      const float* xr1 = &XcB[(16 + jh) * XST + C0];   // row j+1
      const float* xr2 = &XcB[(jh + 1) * XST + C0];    // row j+2
      const float* xr3 = &XcB[(16 + jh + 1) * XST + C0]; // row j+3
      {
        const float4 a = *(const float4*)xr0;
        const float4 b = *(const float4*)(xr0 + 4);
        w0[0] = pka0(s0L, make_float2(a.x, a.y), w0[0]);
        w0[1] = pka0(s0L, make_float2(a.z, a.w), w0[1]);
        w0[2] = pka0(s0L, make_float2(b.x, b.y), w0[2]);
        w0[3] = pka0(s0L, make_float2(b.z, b.w), w0[3]);
        w1[0] = pka0(s1L, make_float2(a.x, a.y), w1[0]);
        w1[1] = pka0(s1L, make_float2(a.z, a.w), w1[1]);
        w1[2] = pka0(s1L, make_float2(b.x, b.y), w1[2]);
        w1[3] = pka0(s1L, make_float2(b.z, b.w), w1[3]);
      }
      {
        const float4 a = *(const float4*)xr1;
        const float4 b = *(const float4*)(xr1 + 4);
        w0[0] = pka1(s0L, make_float2(a.x, a.y), w0[0]);
        w0[1] = pka1(s0L, make_float2(a.z, a.w), w0[1]);
        w0[2] = pka1(s0L, make_float2(b.x, b.y), w0[2]);
        w0[3] = pka1(s0L, make_float2(b.z, b.w), w0[3]);
        w1[0] = pka1(s1L, make_float2(a.x, a.y), w1[0]);
        w1[1] = pka1(s1L, make_float2(a.z, a.w), w1[1]);
        w1[2] = pka1(s1L, make_float2(b.x, b.y), w1[2]);
        w1[3] = pka1(s1L, make_float2(b.z, b.w), w1[3]);
      }
      {
        const float4 a = *(const float4*)xr2;
        const float4 b = *(const float4*)(xr2 + 4);
        w0[0] = pka0(s0H, make_float2(a.x, a.y), w0[0]);
        w0[1] = pka0(s0H, make_float2(a.z, a.w), w0[1]);
        w0[2] = pka0(s0H, make_float2(b.x, b.y), w0[2]);
        w0[3] = pka0(s0H, make_float2(b.z, b.w), w0[3]);
        w1[0] = pka0(s1H, make_float2(a.x, a.y), w1[0]);
        w1[1] = pka0(s1H, make_float2(a.z, a.w), w1[1]);
        w1[2] = pka0(s1H, make_float2(b.x, b.y), w1[2]);
        w1[3] = pka0(s1H, make_float2(b.z, b.w), w1[3]);
      }
      {
        const float4 a = *(const float4*)xr3;
        const float4 b = *(const float4*)(xr3 + 4);
        w0[0] = pka1(s0H, make_float2(a.x, a.y), w0[0]);
        w0[1] = pka1(s0H, make_float2(a.z, a.w), w0[1]);
        w0[2] = pka1(s0H, make_float2(b.x, b.y), w0[2]);
        w0[3] = pka1(s0H, make_float2(b.z, b.w), w0[3]);
        w1[0] = pka1(s1H, make_float2(a.x, a.y), w1[0]);
        w1[1] = pka1(s1H, make_float2(a.z, a.w), w1[1]);
        w1[2] = pka1(s1H, make_float2(b.x, b.y), w1[2]);
        w1[3] = pka1(s1H, make_float2(b.z, b.w), w1[3]);
      }
    }
    // W row 2s2 -> slot s2, row 2s2+1 -> slot 16+s2 (same sigma layout)
    *(float4*)&WB[s2 * XST + C0]     = make_float4(w0[0].x, w0[0].y, w0[1].x, w0[1].y);
    *(float4*)&WB[s2 * XST + C0 + 4] = make_float4(w0[2].x, w0[2].y, w0[3].x, w0[3].y);
    *(float4*)&WB[(16 + s2) * XST + C0]     = make_float4(w1[0].x, w1[0].y, w1[1].x, w1[1].y);
    *(float4*)&WB[(16 + s2) * XST + C0 + 4] = make_float4(w1[2].x, w1[2].y, w1[3].x, w1[3].y);
  }
  __syncthreads();

  // ---- P4: P = Xc^T W, symmetric: 136 diag+upper 8x8 tiles, 2 threads
  //      (4-col halves) per tile. Lower triangle via in-register transpose
  //      mirror stores. Xc and W share the sigma layout, so iterating the
  //      physical slot u pairs matching logical rows in both. ----
  if (t < 272) {
    const int L = t >> 1;
    const int half = t & 1;
    const float fs = sqrtf(1089.0f - 8.0f * (float)L);
    const int R = (int)floorf((33.0f - fs) * 0.5f);
    const int C = R + L - (R * (33 - R)) / 2;
    const int r8 = R << 3;
    const int cb = (C << 3) + (half << 2);

    float2 aP[8][2];
    #pragma unroll
    for (int r = 0; r < 8; ++r) {
      aP[r][0] = make_float2(0.f, 0.f);
      aP[r][1] = make_float2(0.f, 0.f);
    }
    #pragma unroll 4
    for (int u = 0; u < 32; ++u) {
      const float4 cv0 = *(const float4*)&XcB[u * XST + r8];
      const float4 cv1 = *(const float4*)&XcB[u * XST + r8 + 4];
      const float4 rv  = *(const float4*)&WB[u * XST + cb];
      const float2 rL = make_float2(rv.x, rv.y), rH = make_float2(rv.z, rv.w);
      const float2 c01 = make_float2(cv0.x, cv0.y), c23 = make_float2(cv0.z, cv0.w);
      const float2 c45 = make_float2(cv1.x, cv1.y), c67 = make_float2(cv1.z, cv1.w);
      aP[0][0] = pka0(c01, rL, aP[0][0]); aP[0][1] = pka0(c01, rH, aP[0][1]);
      aP[1][0] = pka1(c01, rL, aP[1][0]); aP[1][1] = pka1(c01, rH, aP[1][1]);
      aP[2][0] = pka0(c23, rL, aP[2][0]); aP[2][1] = pka0(c23, rH, aP[2][1]);
      aP[3][0] = pka1(c23, rL, aP[3][0]); aP[3][1] = pka1(c23, rH, aP[3][1]);
      aP[4][0] = pka0(c45, rL, aP[4][0]); aP[4][1] = pka0(c45, rH, aP[4][1]);
      aP[5][0] = pka1(c45, rL, aP[5][0]); aP[5][1] = pka1(c45, rH, aP[5][1]);
      aP[6][0] = pka0(c67, rL, aP[6][0]); aP[6][1] = pka0(c67, rH, aP[6][1]);
      aP[7][0] = pka1(c67, rL, aP[7][0]); aP[7][1] = pka1(c67, rH, aP[7][1]);
    }

    const float ILAM = 1.0f / LAMV;
    const float IL31 = ILAM / 31.0f;
    float* o = out + (size_t)NC * HW + (size_t)pos * (NC * NC);

    // direct store (upper/diag): rows r8..r8+7, cols cb..cb+3
    #pragma unroll
    for (int r = 0; r < 8; ++r) {
      const int gr = r8 + r;
      float4 w;
      w.x = fmaf(-IL31, aP[r][0].x, (gr == cb + 0) ? ILAM : 0.f);
      w.y = fmaf(-IL31, aP[r][0].y, (gr == cb + 1) ? ILAM : 0.f);
      w.z = fmaf(-IL31, aP[r][1].x, (gr == cb + 2) ? ILAM : 0.f);
      w.w = fmaf(-IL31, aP[r][1].y, (gr == cb + 3) ? ILAM : 0.f);
      *(float4*)&o[(size_t)gr * NC + cb] = w;
    }

    // mirror store (strict lower): rows cb..cb+3, cols r8..r8+7
    if (R != C) {
      {
        const float4 m0 = make_float4(-IL31 * aP[0][0].x, -IL31 * aP[1][0].x,
                                      -IL31 * aP[2][0].x, -IL31 * aP[3][0].x);
        const float4 m1 = make_float4(-IL31 * aP[4][0].x, -IL31 * aP[5][0].x,
                                      -IL31 * aP[6][0].x, -IL31 * aP[7][0].x);
        *(float4*)&o[(size_t)(cb + 0) * NC + r8] = m0;
        *(float4*)&o[(size_t)(cb + 0) * NC + r8 + 4] = m1;
      }
      {
        const float4 m0 = make_float4(-IL31 * aP[0][0].y, -IL31 * aP[1][0].y,
                                      -IL31 * aP[2][0].y, -IL31 * aP[3][0].y);
        const float4 m1 = make_float4(-IL31 * aP[4][0].y, -IL31 * aP[5][0].y,
                                      -IL31 * aP[6][0].y, -IL31 * aP[7][0].y);
        *(float4*)&o[(size_t)(cb + 1) * NC + r8] = m0;
        *(float4*)&o[(size_t)(cb + 1) * NC + r8 + 4] = m1;
      }
      {
        const float4 m0 = make_float4(-IL31 * aP[0][1].x, -IL31 * aP[1][1].x,
                                      -IL31 * aP[2][1].x, -IL31 * aP[3][1].x);
        const float4 m1 = make_float4(-IL31 * aP[4][1].x, -IL31 * aP[5][1].x,
                                      -IL31 * aP[6][1].x, -IL31 * aP[7][1].x);
        *(float4*)&o[(size_t)(cb + 2) * NC + r8] = m0;
        *(float4*)&o[(size_t)(cb + 2) * NC + r8 + 4] = m1;
      }
      {
        const float4 m0 = make_float4(-IL31 * aP[0][1].y, -IL31 * aP[1][1].y,
                                      -IL31 * aP[2][1].y, -IL31 * aP[3][1].y);
        const float4 m1 = make_float4(-IL31 * aP[4][1].y, -IL31 * aP[5][1].y,
                                      -IL31 * aP[6][1].y, -IL31 * aP[7][1].y);
        *(float4*)&o[(size_t)(cb + 3) * NC + r8] = m0;
        *(float4*)&o[(size_t)(cb + 3) * NC + r8 + 4] = m1;
      }
    }
  }
}

extern "C" void kernel_launch(void* const* d_in, const int* in_sizes, int n_in,
                              void* d_out, int out_size, void* d_ws, size_t ws_size,
                              hipStream_t stream) {
  const float* emb = (const float*)d_in[0];
  float* out = (float*)d_out;
  mvg_kernel<<<HW, 512, 0, stream>>>(emb, out);
}